// Round 1
// baseline (53.179 us; speedup 1.0000x reference)
//
#include <hip/hip_runtime.h>

// EMA: y[t] = a*x[t] + (1-a)*y[t-1], y_prev init = x[0]  (so y[0] == x[0]).
// Key fact: (1-a)=0.7 decays below fp32 resolution in ~52 steps, so each
// output depends only on the trailing K=64 inputs. We therefore parallelize
// the "serial" scan: each thread warm-starts its carry from a K-element halo
// (abs error <= 0.7^63 ~ 1.7e-10) then runs the exact recurrence over its own
// R-element segment. Segments near t=0 clamp the warm-up to t=0 and are exact.

#define EMA_ALPHA 0.3f
#define EMA_BETA  0.7f
#define BLOCK 256
#define R     32                 // outputs per thread
#define TILE  (BLOCK * R)        // 8192 elements per block
#define K     64                 // warm-up halo length

// skew: per-thread segments are stride-32 in LDS; +1 word every 32 makes
// lane i hit bank (i + c) % 32 -> 2 lanes/bank for wave64 (free, m136).
__device__ __forceinline__ int skew(int i) { return i + (i >> 5); }

__global__ __launch_bounds__(BLOCK) void ema_kernel(
    const float* __restrict__ x, float* __restrict__ y,
    int T, int tilesPerRow) {
  __shared__ float lds[TILE + K + ((TILE + K) >> 5) + 1];

  const int tid      = threadIdx.x;
  const int row      = blockIdx.x / tilesPerRow;
  const int tile     = blockIdx.x % tilesPerRow;
  const int tile_t0  = tile * TILE;
  const float* xrow  = x + (size_t)row * (size_t)T;
  float*       yrow  = y + (size_t)row * (size_t)T;

  // ---- Phase 1: coalesced global -> LDS (tile + left halo), float4 ----
  // LDS position p corresponds to global t = tile_t0 - K + p.
  const int NV = (TILE + K) / 4;  // 2064 float4s
  for (int p4 = tid; p4 < NV; p4 += BLOCK) {
    const int p = p4 * 4;
    const int t = tile_t0 - K + p;           // multiple of 4 (tile_t0%64==0)
    if (t >= 0) {                            // t<0 halo only in first tile; never read
      const float4 v = *reinterpret_cast<const float4*>(xrow + t);
      lds[skew(p    )] = v.x;
      lds[skew(p + 1)] = v.y;
      lds[skew(p + 2)] = v.z;
      lds[skew(p + 3)] = v.w;
    }
  }
  __syncthreads();

  // ---- Phase 2: warm-up carry over [s, t0) ----
  const int t0 = tile_t0 + tid * R;          // this thread's first output index
  const int s  = (t0 - K > 0) ? (t0 - K) : 0;
  int ps = s - tile_t0 + K;                  // LDS position of s
  float carry = lds[skew(ps)];               // approx y[s] (exact x[0] when s==0)
  const int nwu = t0 - 1 - s;                // 63 steps in steady state
  for (int it = 0; it < nwu; ++it) {
    ++ps;
    carry = fmaf(EMA_ALPHA, lds[skew(ps)], EMA_BETA * carry);
  }
  __syncthreads();   // all carries read the pristine tile before phase 3 writes

  // ---- Phase 3: exact in-place scan of own segment ----
  const int p0 = K + tid * R;
#pragma unroll
  for (int j = 0; j < R; ++j) {
    const float v = lds[skew(p0 + j)];
    carry = fmaf(EMA_ALPHA, v, EMA_BETA * carry);
    lds[skew(p0 + j)] = carry;
  }
  __syncthreads();

  // ---- Phase 4: coalesced LDS -> global store, float4 ----
  for (int p4 = tid; p4 < TILE / 4; p4 += BLOCK) {
    const int p = p4 * 4;
    float4 v;
    v.x = lds[skew(K + p    )];
    v.y = lds[skew(K + p + 1)];
    v.z = lds[skew(K + p + 2)];
    v.w = lds[skew(K + p + 3)];
    *reinterpret_cast<float4*>(yrow + tile_t0 + p) = v;
  }
}

extern "C" void kernel_launch(void* const* d_in, const int* in_sizes, int n_in,
                              void* d_out, int out_size, void* d_ws, size_t ws_size,
                              hipStream_t stream) {
  const float* x = (const float*)d_in[0];
  float* y = (float*)d_out;

  const int T = 65536;                 // per problem spec
  const int B = in_sizes[0] / T;       // 512
  const int tilesPerRow = T / TILE;    // 8
  const int grid = B * tilesPerRow;    // 4096 blocks

  ema_kernel<<<grid, BLOCK, 0, stream>>>(x, y, T, tilesPerRow);
}